// Round 4
// baseline (1874.306 us; speedup 1.0000x reference)
//
#include <hip/hip_runtime.h>

#define N_NODES 100000
#define N_EDGES 3200000
#define N_GRAPHS 5000
#define BN_EPS 1e-5f
#define NPAD 100096  // 391 * 256

// ---------- node encoder: h = x @ node_w + node_b   [N,14]@[14,32] ----------
__global__ void k_encode(const float* __restrict__ x, const float* __restrict__ W,
                         const float* __restrict__ b, float* __restrict__ h) {
    __shared__ float sW[448];
    __shared__ float sb[32];
    for (int i = threadIdx.x; i < 448; i += 256) sW[i] = W[i];
    if (threadIdx.x < 32) sb[threadIdx.x] = b[threadIdx.x];
    __syncthreads();
    int n = blockIdx.x * 256 + threadIdx.x;
    if (n >= N_NODES) return;
    float xi[14];
#pragma unroll
    for (int k = 0; k < 14; k++) xi[k] = x[n * 14 + k];
    float4* hp = (float4*)(h + (size_t)n * 32);
#pragma unroll
    for (int q = 0; q < 8; q++) {
        float4 acc;
        float* ap = (float*)&acc;
#pragma unroll
        for (int i = 0; i < 4; i++) {
            int c = q * 4 + i;
            float a = sb[c];
#pragma unroll
            for (int k = 0; k < 14; k++) a += xi[k] * sW[k * 32 + c];
            ap[i] = a;
        }
        hp[q] = acc;
    }
}

// ---------- CSR build (once per call; dst is layer-invariant) ----------
__global__ void k_hist(const int* __restrict__ ei, int* __restrict__ cnt) {
    int e = blockIdx.x * 256 + threadIdx.x;
    if (e >= N_EDGES) return;
    atomicAdd(&cnt[ei[N_EDGES + e]], 1);
}

__global__ void k_scan1(const int* __restrict__ cnt, int* __restrict__ bsum) {
    __shared__ int s[256];
    int i = blockIdx.x * 256 + threadIdx.x;
    s[threadIdx.x] = cnt[i];
    __syncthreads();
    for (int off = 128; off > 0; off >>= 1) {
        if (threadIdx.x < off) s[threadIdx.x] += s[threadIdx.x + off];
        __syncthreads();
    }
    if (threadIdx.x == 0) bsum[blockIdx.x] = s[0];
}

__global__ void k_scan2(const int* __restrict__ bsum, int* __restrict__ boff) {
    if (threadIdx.x == 0 && blockIdx.x == 0) {
        int acc = 0;
        for (int i = 0; i < NPAD / 256; i++) { boff[i] = acc; acc += bsum[i]; }
    }
}

__global__ void k_scan3(const int* __restrict__ cnt, const int* __restrict__ boff,
                        int* __restrict__ offs, int* __restrict__ cursor) {
    __shared__ int s[256];
    int i = blockIdx.x * 256 + threadIdx.x;
    int v = cnt[i];
    s[threadIdx.x] = v;
    __syncthreads();
#pragma unroll
    for (int off = 1; off < 256; off <<= 1) {
        int add = (threadIdx.x >= off) ? s[threadIdx.x - off] : 0;
        __syncthreads();
        s[threadIdx.x] += add;
        __syncthreads();
    }
    int excl = s[threadIdx.x] - v + boff[blockIdx.x];
    offs[i] = excl;
    cursor[i] = excl;
    if (i == NPAD - 1) offs[NPAD] = excl + v;
}

// packed[j] = (ea0, ea1, ea2, src_as_float) sorted by dst
__global__ void k_scatter(const int* __restrict__ ei, const float* __restrict__ ea,
                          int* __restrict__ cursor, float4* __restrict__ packed) {
    int e = blockIdx.x * 256 + threadIdx.x;
    if (e >= N_EDGES) return;
    int src = ei[e];
    int dst = ei[N_EDGES + e];
    float a0 = ea[(size_t)e * 3 + 0], a1 = ea[(size_t)e * 3 + 1], a2 = ea[(size_t)e * 3 + 2];
    int j = atomicAdd(&cursor[dst], 1);
    packed[j] = make_float4(a0, a1, a2, __int_as_float(src));
}

// ---------- W1 transpose: [2][32][75] -> [2][75][32] (once per call) ----------
__global__ void k_wt(const float* __restrict__ W1, float* __restrict__ W1T) {
    int i = blockIdx.x * 256 + threadIdx.x;
    if (i >= 2 * 2400) return;
    int l = i / 2400, r = i % 2400;
    int c = r / 75, j = r % 75;
    W1T[l * 2400 + j * 32 + c] = W1[i];
}

// ---------- pull aggregation: agg[n] = sum_j relu(h[src_j] + ea_j@eW + eb), no atomics ----------
__global__ void __launch_bounds__(256) k_agg(const float4* __restrict__ packed,
                                             const int* __restrict__ offs,
                                             const float* __restrict__ eW, const float* __restrict__ eb,
                                             const float* __restrict__ h, float* __restrict__ agg) {
    int t = blockIdx.x * 256 + threadIdx.x;
    int n = t >> 3, q = t & 7;
    if (n >= N_NODES) return;
    int c0 = q * 4;
    float w0[4], w1[4], w2[4], bb[4];
#pragma unroll
    for (int i = 0; i < 4; i++) {
        w0[i] = eW[c0 + i];
        w1[i] = eW[32 + c0 + i];
        w2[i] = eW[64 + c0 + i];
        bb[i] = eb[c0 + i];
    }
    int beg = offs[n], end = offs[n + 1];
    float acc[4] = {0.f, 0.f, 0.f, 0.f};
    for (int j = beg; j < end; j++) {
        float4 p = packed[j];
        int src = __float_as_int(p.w);
        float4 hs = *(const float4*)(h + (size_t)src * 32 + c0);
        const float* hp = (const float*)&hs;
#pragma unroll
        for (int i = 0; i < 4; i++) {
            float m = hp[i] + p.x * w0[i] + p.y * w1[i] + p.z * w2[i] + bb[i];
            acc[i] += fmaxf(m, 0.f);
        }
    }
    float4 o = make_float4(acc[0], acc[1], acc[2], acc[3]);
    *(float4*)(agg + (size_t)n * 32 + c0) = o;
}

// ---------- z = relu((h+agg)@W1+b1)@W2+b2, in-place over agg; per-channel sum/sumsq ----------
// Weights read via wave-uniform indices -> scalar (s_load) path, no LDS.
// GEMM1/GEMM2 fused per hidden unit j; hj reduction uses a 4-way partial tree.
__global__ void __launch_bounds__(256) k_update(const float* __restrict__ h, float* __restrict__ zio,
                                                const float* __restrict__ W1T, const float* __restrict__ b1,
                                                const float* __restrict__ W2, const float* __restrict__ b2,
                                                float* __restrict__ stats) {
    int n = blockIdx.x * 256 + threadIdx.x;
    bool valid = n < N_NODES;
    const size_t base = (size_t)(valid ? n : 0) * 32;

    float zc[32];
#pragma unroll
    for (int q = 0; q < 8; q++) {
        float4 hv = *(const float4*)(h + base + q * 4);
        float4 av = *(const float4*)(zio + base + q * 4);
        zc[q * 4 + 0] = hv.x + av.x;
        zc[q * 4 + 1] = hv.y + av.y;
        zc[q * 4 + 2] = hv.z + av.z;
        zc[q * 4 + 3] = hv.w + av.w;
    }

    float zo[32];
#pragma unroll
    for (int c = 0; c < 32; c++) zo[c] = b2[c];

#pragma unroll 5
    for (int j = 0; j < 75; j++) {
        const float* w1 = W1T + j * 32;   // uniform address -> s_load
        float p0 = 0.f, p1 = 0.f, p2 = 0.f, p3 = 0.f;
#pragma unroll
        for (int c = 0; c < 8; c++) {
            p0 += zc[c * 4 + 0] * w1[c * 4 + 0];
            p1 += zc[c * 4 + 1] * w1[c * 4 + 1];
            p2 += zc[c * 4 + 2] * w1[c * 4 + 2];
            p3 += zc[c * 4 + 3] * w1[c * 4 + 3];
        }
        float hj = fmaxf(b1[j] + ((p0 + p1) + (p2 + p3)), 0.f);
        const float* w2 = W2 + j * 32;    // uniform address -> s_load
#pragma unroll
        for (int c = 0; c < 32; c++) zo[c] += hj * w2[c];
    }

    if (valid) {
#pragma unroll
        for (int q = 0; q < 8; q++) {
            float4 o = make_float4(zo[q * 4], zo[q * 4 + 1], zo[q * 4 + 2], zo[q * 4 + 3]);
            *(float4*)(zio + base + q * 4) = o;
        }
    }

    // per-channel sum / sumsq for BN
    int lane = threadIdx.x & 63;
#pragma unroll
    for (int c = 0; c < 32; c++) {
        float s = valid ? zo[c] : 0.f;
        float s2 = valid ? zo[c] * zo[c] : 0.f;
#pragma unroll
        for (int off = 32; off > 0; off >>= 1) {
            s += __shfl_down(s, off, 64);
            s2 += __shfl_down(s2, off, 64);
        }
        if (lane == 0) { atomicAdd(&stats[c], s); atomicAdd(&stats[32 + c], s2); }
    }
}

// ---------- h = relu((z - mu) * g * rsqrt(var+eps) + b) ----------
__global__ void k_bn(const float* __restrict__ z, float* __restrict__ h,
                     const float* __restrict__ stats, const float* __restrict__ g,
                     const float* __restrict__ b) {
    int t = blockIdx.x * 256 + threadIdx.x;
    if (t >= N_NODES * 8) return;
    int q = t & 7;
    float4 zv = ((const float4*)z)[t];
    float* zp = (float*)&zv;
    float4 ov;
    float* op = (float*)&ov;
    const float invN = 1.0f / (float)N_NODES;
#pragma unroll
    for (int i = 0; i < 4; i++) {
        int c = q * 4 + i;
        float mu = stats[c] * invN;
        float var = stats[32 + c] * invN - mu * mu;
        float sc = g[c] / sqrtf(var + BN_EPS);
        float val = (zp[i] - mu) * sc + b[c];
        op[i] = fmaxf(val, 0.f);
    }
    ((float4*)h)[t] = ov;
}

__global__ void k_pool(const float* __restrict__ h, const int* __restrict__ batch,
                       float* __restrict__ gsum, float* __restrict__ gcnt) {
    int t = blockIdx.x * 256 + threadIdx.x;
    if (t >= N_NODES * 8) return;
    int n = t >> 3, q = t & 7;
    int g = batch[n];
    float4 hv = ((const float4*)h)[t];
    float* hp = (float*)&hv;
    float* gp = gsum + (size_t)g * 32 + q * 4;
#pragma unroll
    for (int i = 0; i < 4; i++) atomicAdd(gp + i, hp[i]);
    if (q == 0) atomicAdd(&gcnt[g], 1.0f);
}

__global__ void k_head(const float* __restrict__ gsum, const float* __restrict__ gcnt,
                       const float* __restrict__ W1, const float* __restrict__ b1,
                       const float* __restrict__ W2, const float* __restrict__ b2,
                       float* __restrict__ out) {
    __shared__ float sW1[512], sb1[16], sW2[32], sb2[2];
    for (int i = threadIdx.x; i < 512; i += 256) sW1[i] = W1[i];
    if (threadIdx.x < 16) sb1[threadIdx.x] = b1[threadIdx.x];
    if (threadIdx.x < 32) sW2[threadIdx.x] = W2[threadIdx.x];
    if (threadIdx.x < 2) sb2[threadIdx.x] = b2[threadIdx.x];
    __syncthreads();
    int gI = blockIdx.x * 256 + threadIdx.x;
    if (gI >= N_GRAPHS) return;
    float cnt = fmaxf(gcnt[gI], 1.0f);
    float inv = 1.0f / cnt;
    float gx[32];
#pragma unroll
    for (int c = 0; c < 32; c++) gx[c] = gsum[(size_t)gI * 32 + c] * inv;
    float hid[16];
#pragma unroll
    for (int j = 0; j < 16; j++) {
        float a = sb1[j];
#pragma unroll
        for (int c = 0; c < 32; c++) a += gx[c] * sW1[c * 16 + j];
        hid[j] = fmaxf(a, 0.f);
    }
#pragma unroll
    for (int o = 0; o < 2; o++) {
        float a = sb2[o];
#pragma unroll
        for (int j = 0; j < 16; j++) a += hid[j] * sW2[j * 2 + o];
        out[(size_t)gI * 2 + o] = a;
    }
}

extern "C" void kernel_launch(void* const* d_in, const int* in_sizes, int n_in,
                              void* d_out, int out_size, void* d_ws, size_t ws_size,
                              hipStream_t stream) {
    const float* x       = (const float*)d_in[0];
    const int*   ei      = (const int*)d_in[1];
    const float* eattr   = (const float*)d_in[2];
    const int*   batch   = (const int*)d_in[3];
    const float* node_w  = (const float*)d_in[4];
    const float* node_b  = (const float*)d_in[5];
    const float* edge_w  = (const float*)d_in[6];
    const float* edge_b  = (const float*)d_in[7];
    const float* conv_w1 = (const float*)d_in[8];
    const float* conv_b1 = (const float*)d_in[9];
    const float* conv_w2 = (const float*)d_in[10];
    const float* conv_b2 = (const float*)d_in[11];
    const float* bn_g    = (const float*)d_in[12];
    const float* bn_b    = (const float*)d_in[13];
    const float* lin1_w  = (const float*)d_in[14];
    const float* lin1_b  = (const float*)d_in[15];
    const float* lin2_w  = (const float*)d_in[16];
    const float* lin2_b  = (const float*)d_in[17];
    float* out = (float*)d_out;

    // workspace layout (packed first for 16B alignment)
    float4* packed = (float4*)d_ws;                        // E float4 = 51.2 MB
    float*  h      = (float*)(packed + N_EDGES);           // N*32
    float*  agg    = h + (size_t)N_NODES * 32;             // N*32 (z in-place)
    int*    cnt    = (int*)(agg + (size_t)N_NODES * 32);   // NPAD
    int*    offs   = cnt + NPAD;                           // NPAD+1
    int*    cursor = offs + NPAD + 1;                      // NPAD
    int*    bsum   = cursor + NPAD;                        // NPAD/256
    int*    boff   = bsum + NPAD / 256;                    // NPAD/256
    float*  stats  = (float*)(boff + NPAD / 256);          // 64
    float*  gsum   = stats + 64;                           // G*32
    float*  gcnt   = gsum + (size_t)N_GRAPHS * 32;         // G
    float*  w1t    = gcnt + N_GRAPHS;                      // 2*2400

    int nb_nodes = (N_NODES + 255) / 256;
    int nb_edges = (N_EDGES + 255) / 256;
    int nb_vec   = (N_NODES * 8 + 255) / 256;
    int nb_scan  = NPAD / 256;                             // 391

    hipMemsetAsync(cnt, 0, NPAD * sizeof(int), stream);
    k_encode<<<nb_nodes, 256, 0, stream>>>(x, node_w, node_b, h);
    k_wt<<<(4800 + 255) / 256, 256, 0, stream>>>(conv_w1, w1t);
    k_hist<<<nb_edges, 256, 0, stream>>>(ei, cnt);
    k_scan1<<<nb_scan, 256, 0, stream>>>(cnt, bsum);
    k_scan2<<<1, 64, 0, stream>>>(bsum, boff);
    k_scan3<<<nb_scan, 256, 0, stream>>>(cnt, boff, offs, cursor);
    k_scatter<<<nb_edges, 256, 0, stream>>>(ei, eattr, cursor, packed);

    for (int l = 0; l < 2; l++) {
        hipMemsetAsync(stats, 0, 64 * sizeof(float), stream);
        k_agg<<<NPAD * 8 / 256, 256, 0, stream>>>(packed, offs, edge_w, edge_b, h, agg);
        k_update<<<nb_nodes, 256, 0, stream>>>(h, agg, w1t + l * 2400, conv_b1 + l * 75,
                                               conv_w2 + l * 2400, conv_b2 + l * 32, stats);
        k_bn<<<nb_vec, 256, 0, stream>>>(agg, h, stats, bn_g + l * 32, bn_b + l * 32);
    }
    hipMemsetAsync(gsum, 0, ((size_t)N_GRAPHS * 32 + N_GRAPHS) * sizeof(float), stream);
    k_pool<<<nb_vec, 256, 0, stream>>>(h, batch, gsum, gcnt);
    k_head<<<(N_GRAPHS + 255) / 256, 256, 0, stream>>>(gsum, gcnt, lin1_w, lin1_b, lin2_w, lin2_b, out);
}

// Round 5
// 1236.934 us; speedup vs baseline: 1.5153x; 1.5153x over previous
//
#include <hip/hip_runtime.h>

#define N_NODES 100000
#define N_EDGES 3200000
#define N_GRAPHS 5000
#define BN_EPS 1e-5f
#define NPAD 100096   // 391 * 256
#define HPAD 80       // hidden 75 padded to 80 (16B-aligned float4 rows, zero pad)

// ---------- node encoder: h = x @ node_w + node_b   [N,14]@[14,32] ----------
__global__ void k_encode(const float* __restrict__ x, const float* __restrict__ W,
                         const float* __restrict__ b, float* __restrict__ h) {
    __shared__ float sW[448];
    __shared__ float sb[32];
    for (int i = threadIdx.x; i < 448; i += 256) sW[i] = W[i];
    if (threadIdx.x < 32) sb[threadIdx.x] = b[threadIdx.x];
    __syncthreads();
    int n = blockIdx.x * 256 + threadIdx.x;
    if (n >= N_NODES) return;
    float xi[14];
#pragma unroll
    for (int k = 0; k < 14; k++) xi[k] = x[n * 14 + k];
    float4* hp = (float4*)(h + (size_t)n * 32);
#pragma unroll
    for (int q = 0; q < 8; q++) {
        float4 acc;
        float* ap = (float*)&acc;
#pragma unroll
        for (int i = 0; i < 4; i++) {
            int c = q * 4 + i;
            float a = sb[c];
#pragma unroll
            for (int k = 0; k < 14; k++) a += xi[k] * sW[k * 32 + c];
            ap[i] = a;
        }
        hp[q] = acc;
    }
}

// ---------- CSR build (once per call; dst is layer-invariant) ----------
__global__ void k_hist(const int* __restrict__ ei, int* __restrict__ cnt) {
    int e = blockIdx.x * 256 + threadIdx.x;
    if (e >= N_EDGES) return;
    atomicAdd(&cnt[ei[N_EDGES + e]], 1);
}

__global__ void k_scan1(const int* __restrict__ cnt, int* __restrict__ bsum) {
    __shared__ int s[256];
    int i = blockIdx.x * 256 + threadIdx.x;
    s[threadIdx.x] = cnt[i];
    __syncthreads();
    for (int off = 128; off > 0; off >>= 1) {
        if (threadIdx.x < off) s[threadIdx.x] += s[threadIdx.x + off];
        __syncthreads();
    }
    if (threadIdx.x == 0) bsum[blockIdx.x] = s[0];
}

__global__ void k_scan2(const int* __restrict__ bsum, int* __restrict__ boff) {
    if (threadIdx.x == 0 && blockIdx.x == 0) {
        int acc = 0;
        for (int i = 0; i < NPAD / 256; i++) { boff[i] = acc; acc += bsum[i]; }
    }
}

__global__ void k_scan3(const int* __restrict__ cnt, const int* __restrict__ boff,
                        int* __restrict__ offs, int* __restrict__ cursor) {
    __shared__ int s[256];
    int i = blockIdx.x * 256 + threadIdx.x;
    int v = cnt[i];
    s[threadIdx.x] = v;
    __syncthreads();
#pragma unroll
    for (int off = 1; off < 256; off <<= 1) {
        int add = (threadIdx.x >= off) ? s[threadIdx.x - off] : 0;
        __syncthreads();
        s[threadIdx.x] += add;
        __syncthreads();
    }
    int excl = s[threadIdx.x] - v + boff[blockIdx.x];
    offs[i] = excl;
    cursor[i] = excl;
    if (i == NPAD - 1) offs[NPAD] = excl + v;
}

// packed[j] = (ea0, ea1, ea2, src_as_float) sorted by dst
__global__ void k_scatter(const int* __restrict__ ei, const float* __restrict__ ea,
                          int* __restrict__ cursor, float4* __restrict__ packed) {
    int e = blockIdx.x * 256 + threadIdx.x;
    if (e >= N_EDGES) return;
    int src = ei[e];
    int dst = ei[N_EDGES + e];
    float a0 = ea[(size_t)e * 3 + 0], a1 = ea[(size_t)e * 3 + 1], a2 = ea[(size_t)e * 3 + 2];
    int j = atomicAdd(&cursor[dst], 1);
    packed[j] = make_float4(a0, a1, a2, __int_as_float(src));
}

// ---------- weight prep: transpose + zero-pad (once per call) ----------
// w1tp[l][j(80)][c(32)]  (rows j>=75 zero)
// b1p [l][j(80)]         (j>=75 zero)
// w2tp[l][c(32)][j(80)]  (cols j>=75 zero)
__global__ void k_prep(const float* __restrict__ W1, const float* __restrict__ b1,
                       const float* __restrict__ W2,
                       float* __restrict__ w1tp, float* __restrict__ b1p,
                       float* __restrict__ w2tp) {
    int i = blockIdx.x * 256 + threadIdx.x;
    if (i < 2 * HPAD * 32) {
        int l = i / (HPAD * 32), r = i % (HPAD * 32);
        int j = r / 32, c = r % 32;
        w1tp[i] = (j < 75) ? W1[l * 2400 + c * 75 + j] : 0.f;
    } else if (i < 2 * HPAD * 32 + 2 * HPAD) {
        int k = i - 2 * HPAD * 32;
        int l = k / HPAD, j = k % HPAD;
        b1p[k] = (j < 75) ? b1[l * 75 + j] : 0.f;
    } else if (i < 2 * HPAD * 32 + 2 * HPAD + 2 * 32 * HPAD) {
        int k = i - (2 * HPAD * 32 + 2 * HPAD);
        int l = k / (32 * HPAD), r = k % (32 * HPAD);
        int c = r / HPAD, j = r % HPAD;
        w2tp[k] = (j < 75) ? W2[l * 2400 + j * 32 + c] : 0.f;
    }
}

// ---------- pull aggregation: agg[n] = sum_j relu(h[src_j] + ea_j@eW + eb), no atomics ----------
__global__ void __launch_bounds__(256) k_agg(const float4* __restrict__ packed,
                                             const int* __restrict__ offs,
                                             const float* __restrict__ eW, const float* __restrict__ eb,
                                             const float* __restrict__ h, float* __restrict__ agg) {
    int t = blockIdx.x * 256 + threadIdx.x;
    int n = t >> 3, q = t & 7;
    if (n >= N_NODES) return;
    int c0 = q * 4;
    float w0[4], w1[4], w2[4], bb[4];
#pragma unroll
    for (int i = 0; i < 4; i++) {
        w0[i] = eW[c0 + i];
        w1[i] = eW[32 + c0 + i];
        w2[i] = eW[64 + c0 + i];
        bb[i] = eb[c0 + i];
    }
    int beg = offs[n], end = offs[n + 1];
    float acc[4] = {0.f, 0.f, 0.f, 0.f};
    for (int j = beg; j < end; j++) {
        float4 p = packed[j];
        int src = __float_as_int(p.w);
        float4 hs = *(const float4*)(h + (size_t)src * 32 + c0);
        const float* hp = (const float*)&hs;
#pragma unroll
        for (int i = 0; i < 4; i++) {
            float m = hp[i] + p.x * w0[i] + p.y * w1[i] + p.z * w2[i] + bb[i];
            acc[i] += fmaxf(m, 0.f);
        }
    }
    float4 o = make_float4(acc[0], acc[1], acc[2], acc[3]);
    *(float4*)(agg + (size_t)n * 32 + c0) = o;
}

// ---------- MLP stage 1: hid[n][j] = relu(b1[j] + (h[n]+agg[n]) . W1T[j])  ----------
// one thread per (node, hidden-unit); 8M threads, ~20 VGPRs, no spill possible
__global__ void __launch_bounds__(256) k_mlp1(const float* __restrict__ h, const float* __restrict__ agg,
                                              const float* __restrict__ W, const float* __restrict__ B,
                                              float* __restrict__ hid) {
    unsigned t = blockIdx.x * 256 + threadIdx.x;   // < N_NODES * HPAD (exact multiple)
    unsigned n = t / HPAD;
    unsigned j = t - n * HPAD;
    const float4* hp = (const float4*)(h + (size_t)n * 32);
    const float4* ap = (const float4*)(agg + (size_t)n * 32);
    const float4* wp = (const float4*)(W + j * 32);
    float acc0 = 0.f, acc1 = 0.f, acc2 = 0.f, acc3 = 0.f;
#pragma unroll
    for (int q = 0; q < 8; q++) {
        float4 hv = hp[q];
        float4 av = ap[q];
        float4 wv = wp[q];
        acc0 += (hv.x + av.x) * wv.x;
        acc1 += (hv.y + av.y) * wv.y;
        acc2 += (hv.z + av.z) * wv.z;
        acc3 += (hv.w + av.w) * wv.w;
    }
    float v = B[j] + ((acc0 + acc1) + (acc2 + acc3));
    hid[(size_t)n * HPAD + j] = fmaxf(v, 0.f);   // pad rows are zero-weight => exact 0
}

// ---------- MLP stage 2: z[n][c] = b2[c] + hid[n] . W2T[c]  (dot over 80, pads are 0) ----------
__global__ void __launch_bounds__(256) k_mlp2(const float* __restrict__ hid,
                                              const float* __restrict__ W2T, const float* __restrict__ b2,
                                              float* __restrict__ z) {
    unsigned t = blockIdx.x * 256 + threadIdx.x;   // < N_NODES * 32 (exact multiple)
    unsigned n = t >> 5;
    unsigned c = t & 31;
    const float4* hp = (const float4*)(hid + (size_t)n * HPAD);
    const float4* wp = (const float4*)(W2T + c * HPAD);
    float acc0 = 0.f, acc1 = 0.f, acc2 = 0.f, acc3 = 0.f;
#pragma unroll
    for (int q = 0; q < 20; q++) {
        float4 hv = hp[q];
        float4 wv = wp[q];
        acc0 += hv.x * wv.x;
        acc1 += hv.y * wv.y;
        acc2 += hv.z * wv.z;
        acc3 += hv.w * wv.w;
    }
    z[t] = b2[c] + ((acc0 + acc1) + (acc2 + acc3));
}

// ---------- BN stats: per-channel sum / sumsq over z  ----------
__global__ void __launch_bounds__(256) k_stats(const float* __restrict__ z, float* __restrict__ stats) {
    __shared__ float ls[4 * 64];
    int tid = threadIdx.x;
    int c = tid & 31;
    float s = 0.f, s2 = 0.f;
    for (int e = blockIdx.x * 256 + tid; e < N_NODES * 32; e += 256 * 256) {
        float v = z[e];
        s += v; s2 += v * v;
    }
    s += __shfl_down(s, 32, 64);     // combine the two nodes sharing this wave
    s2 += __shfl_down(s2, 32, 64);
    int wave = tid >> 6, lane = tid & 63;
    if (lane < 32) { ls[wave * 64 + c] = s; ls[wave * 64 + 32 + c] = s2; }
    __syncthreads();
    if (tid < 64) {
        float a = ls[tid] + ls[64 + tid] + ls[128 + tid] + ls[192 + tid];
        atomicAdd(&stats[tid], a);
    }
}

// ---------- h = relu((z - mu) * g * rsqrt(var+eps) + b) ----------
__global__ void k_bn(const float* __restrict__ z, float* __restrict__ h,
                     const float* __restrict__ stats, const float* __restrict__ g,
                     const float* __restrict__ b) {
    int t = blockIdx.x * 256 + threadIdx.x;
    if (t >= N_NODES * 8) return;
    int q = t & 7;
    float4 zv = ((const float4*)z)[t];
    float* zp = (float*)&zv;
    float4 ov;
    float* op = (float*)&ov;
    const float invN = 1.0f / (float)N_NODES;
#pragma unroll
    for (int i = 0; i < 4; i++) {
        int c = q * 4 + i;
        float mu = stats[c] * invN;
        float var = stats[32 + c] * invN - mu * mu;
        float sc = g[c] / sqrtf(var + BN_EPS);
        float val = (zp[i] - mu) * sc + b[c];
        op[i] = fmaxf(val, 0.f);
    }
    ((float4*)h)[t] = ov;
}

__global__ void k_pool(const float* __restrict__ h, const int* __restrict__ batch,
                       float* __restrict__ gsum, float* __restrict__ gcnt) {
    int t = blockIdx.x * 256 + threadIdx.x;
    if (t >= N_NODES * 8) return;
    int n = t >> 3, q = t & 7;
    int g = batch[n];
    float4 hv = ((const float4*)h)[t];
    float* hp = (float*)&hv;
    float* gp = gsum + (size_t)g * 32 + q * 4;
#pragma unroll
    for (int i = 0; i < 4; i++) atomicAdd(gp + i, hp[i]);
    if (q == 0) atomicAdd(&gcnt[g], 1.0f);
}

__global__ void k_head(const float* __restrict__ gsum, const float* __restrict__ gcnt,
                       const float* __restrict__ W1, const float* __restrict__ b1,
                       const float* __restrict__ W2, const float* __restrict__ b2,
                       float* __restrict__ out) {
    __shared__ float sW1[512], sb1[16], sW2[32], sb2[2];
    for (int i = threadIdx.x; i < 512; i += 256) sW1[i] = W1[i];
    if (threadIdx.x < 16) sb1[threadIdx.x] = b1[threadIdx.x];
    if (threadIdx.x < 32) sW2[threadIdx.x] = W2[threadIdx.x];
    if (threadIdx.x < 2) sb2[threadIdx.x] = b2[threadIdx.x];
    __syncthreads();
    int gI = blockIdx.x * 256 + threadIdx.x;
    if (gI >= N_GRAPHS) return;
    float cnt = fmaxf(gcnt[gI], 1.0f);
    float inv = 1.0f / cnt;
    float gx[32];
#pragma unroll
    for (int c = 0; c < 32; c++) gx[c] = gsum[(size_t)gI * 32 + c] * inv;
    float hid[16];
#pragma unroll
    for (int j = 0; j < 16; j++) {
        float a = sb1[j];
#pragma unroll
        for (int c = 0; c < 32; c++) a += gx[c] * sW1[c * 16 + j];
        hid[j] = fmaxf(a, 0.f);
    }
#pragma unroll
    for (int o = 0; o < 2; o++) {
        float a = sb2[o];
#pragma unroll
        for (int j = 0; j < 16; j++) a += hid[j] * sW2[j * 2 + o];
        out[(size_t)gI * 2 + o] = a;
    }
}

extern "C" void kernel_launch(void* const* d_in, const int* in_sizes, int n_in,
                              void* d_out, int out_size, void* d_ws, size_t ws_size,
                              hipStream_t stream) {
    const float* x       = (const float*)d_in[0];
    const int*   ei      = (const int*)d_in[1];
    const float* eattr   = (const float*)d_in[2];
    const int*   batch   = (const int*)d_in[3];
    const float* node_w  = (const float*)d_in[4];
    const float* node_b  = (const float*)d_in[5];
    const float* edge_w  = (const float*)d_in[6];
    const float* edge_b  = (const float*)d_in[7];
    const float* conv_w1 = (const float*)d_in[8];
    const float* conv_b1 = (const float*)d_in[9];
    const float* conv_w2 = (const float*)d_in[10];
    const float* conv_b2 = (const float*)d_in[11];
    const float* bn_g    = (const float*)d_in[12];
    const float* bn_b    = (const float*)d_in[13];
    const float* lin1_w  = (const float*)d_in[14];
    const float* lin1_b  = (const float*)d_in[15];
    const float* lin2_w  = (const float*)d_in[16];
    const float* lin2_b  = (const float*)d_in[17];
    float* out = (float*)d_out;

    // workspace layout (16B-aligned chunks first)
    float4* packed = (float4*)d_ws;                        // E float4 = 51.2 MB
    float*  hid    = (float*)(packed + N_EDGES);           // N*80 = 32 MB
    float*  h      = hid + (size_t)N_NODES * HPAD;         // N*32
    float*  agg    = h + (size_t)N_NODES * 32;             // N*32 (z written in-place)
    int*    cnt    = (int*)(agg + (size_t)N_NODES * 32);   // NPAD
    int*    offs   = cnt + NPAD;                           // NPAD+1
    int*    cursor = offs + NPAD + 1;                      // NPAD
    int*    bsum   = cursor + NPAD;                        // NPAD/256
    int*    boff   = bsum + NPAD / 256;                    // NPAD/256
    float*  stats  = (float*)(boff + NPAD / 256);          // 64
    float*  gsum   = stats + 64;                           // G*32
    float*  gcnt   = gsum + (size_t)N_GRAPHS * 32;         // G
    float*  w1tp   = gcnt + N_GRAPHS;                      // 2*80*32
    float*  b1p    = w1tp + 2 * HPAD * 32;                 // 2*80
    float*  w2tp   = b1p + 2 * HPAD;                       // 2*32*80

    int nb_nodes = (N_NODES + 255) / 256;
    int nb_edges = (N_EDGES + 255) / 256;
    int nb_vec   = (N_NODES * 8 + 255) / 256;
    int nb_scan  = NPAD / 256;                             // 391

    hipMemsetAsync(cnt, 0, NPAD * sizeof(int), stream);
    k_encode<<<nb_nodes, 256, 0, stream>>>(x, node_w, node_b, h);
    k_prep<<<(2 * HPAD * 32 + 2 * HPAD + 2 * 32 * HPAD + 255) / 256, 256, 0, stream>>>(
        conv_w1, conv_b1, conv_w2, w1tp, b1p, w2tp);
    k_hist<<<nb_edges, 256, 0, stream>>>(ei, cnt);
    k_scan1<<<nb_scan, 256, 0, stream>>>(cnt, bsum);
    k_scan2<<<1, 64, 0, stream>>>(bsum, boff);
    k_scan3<<<nb_scan, 256, 0, stream>>>(cnt, boff, offs, cursor);
    k_scatter<<<nb_edges, 256, 0, stream>>>(ei, eattr, cursor, packed);

    for (int l = 0; l < 2; l++) {
        hipMemsetAsync(stats, 0, 64 * sizeof(float), stream);
        k_agg<<<NPAD * 8 / 256, 256, 0, stream>>>(packed, offs, edge_w, edge_b, h, agg);
        k_mlp1<<<N_NODES * HPAD / 256, 256, 0, stream>>>(h, agg, w1tp + l * HPAD * 32,
                                                         b1p + l * HPAD, hid);
        k_mlp2<<<N_NODES * 32 / 256, 256, 0, stream>>>(hid, w2tp + l * 32 * HPAD,
                                                       conv_b2 + l * 32, agg);
        k_stats<<<256, 256, 0, stream>>>(agg, stats);
        k_bn<<<nb_vec, 256, 0, stream>>>(agg, h, stats, bn_g + l * 32, bn_b + l * 32);
    }
    hipMemsetAsync(gsum, 0, ((size_t)N_GRAPHS * 32 + N_GRAPHS) * sizeof(float), stream);
    k_pool<<<nb_vec, 256, 0, stream>>>(h, batch, gsum, gcnt);
    k_head<<<(N_GRAPHS + 255) / 256, 256, 0, stream>>>(gsum, gcnt, lin1_w, lin1_b, lin2_w, lin2_b, out);
}

// Round 6
// 1033.566 us; speedup vs baseline: 1.8134x; 1.1968x over previous
//
#include <hip/hip_runtime.h>

#define N_NODES 100000
#define N_EDGES 3200000
#define N_GRAPHS 5000
#define BN_EPS 1e-5f
#define NPAD 100096    // 1564 * 64
#define HPAD 80        // hidden 75 padded to 80
#define CHUNK 16384    // edges per bucket-sort block
#define NBLKA 196      // ceil(N_EDGES / CHUNK)
#define NBKT 1564      // buckets of 64 nodes (dst >> 6)
#define LCM (NBKT * NBLKA)       // 306544 count-matrix entries
#define LALLOC 306688            // LCM padded to 1198*256
#define NS1 1198                 // LALLOC / 256

// ---------- node encoder: h = x @ node_w + node_b ----------
__global__ void k_encode(const float* __restrict__ x, const float* __restrict__ W,
                         const float* __restrict__ b, float* __restrict__ h) {
    __shared__ float sW[448];
    __shared__ float sb[32];
    for (int i = threadIdx.x; i < 448; i += 256) sW[i] = W[i];
    if (threadIdx.x < 32) sb[threadIdx.x] = b[threadIdx.x];
    __syncthreads();
    int n = blockIdx.x * 256 + threadIdx.x;
    if (n >= N_NODES) return;
    float xi[14];
#pragma unroll
    for (int k = 0; k < 14; k++) xi[k] = x[n * 14 + k];
    float4* hp = (float4*)(h + (size_t)n * 32);
#pragma unroll
    for (int q = 0; q < 8; q++) {
        float4 acc;
        float* ap = (float*)&acc;
#pragma unroll
        for (int i = 0; i < 4; i++) {
            int c = q * 4 + i;
            float a = sb[c];
#pragma unroll
            for (int k = 0; k < 14; k++) a += xi[k] * sW[k * 32 + c];
            ap[i] = a;
        }
        hp[q] = acc;
    }
}

// ---------- weight prep (transpose + zero-pad) ----------
__global__ void k_prep(const float* __restrict__ W1, const float* __restrict__ b1,
                       const float* __restrict__ W2,
                       float* __restrict__ w1tp, float* __restrict__ b1p,
                       float* __restrict__ w2tp) {
    int i = blockIdx.x * 256 + threadIdx.x;
    if (i < 2 * HPAD * 32) {
        int l = i / (HPAD * 32), r = i % (HPAD * 32);
        int j = r / 32, c = r % 32;
        w1tp[i] = (j < 75) ? W1[l * 2400 + c * 75 + j] : 0.f;
    } else if (i < 2 * HPAD * 32 + 2 * HPAD) {
        int k = i - 2 * HPAD * 32;
        int l = k / HPAD, j = k % HPAD;
        b1p[k] = (j < 75) ? b1[l * 75 + j] : 0.f;
    } else if (i < 2 * HPAD * 32 + 2 * HPAD + 2 * 32 * HPAD) {
        int k = i - (2 * HPAD * 32 + 2 * HPAD);
        int l = k / (32 * HPAD), r = k % (32 * HPAD);
        int c = r / HPAD, j = r % HPAD;
        w2tp[k] = (j < 75) ? W2[l * 2400 + j * 32 + c] : 0.f;
    }
}

// ---------- bucket sort phase A: per-block bucket histogram (LDS atomics only) ----------
__global__ void __launch_bounds__(256) ksA(const int* __restrict__ ei, int* __restrict__ cmat) {
    __shared__ int lh[NBKT];
    for (int i = threadIdx.x; i < NBKT; i += 256) lh[i] = 0;
    __syncthreads();
    int b0 = blockIdx.x * CHUNK;
    for (int i = threadIdx.x; i < CHUNK; i += 256) {
        int e = b0 + i;
        if (e < N_EDGES) atomicAdd(&lh[ei[N_EDGES + e] >> 6], 1);
    }
    __syncthreads();
    for (int b = threadIdx.x; b < NBKT; b += 256) cmat[b * NBLKA + blockIdx.x] = lh[b];
}

// ---------- parallel exclusive scan of cmat (3 kernels) ----------
__global__ void ks1(const int* __restrict__ a, int* __restrict__ bs) {
    __shared__ int s[256];
    int i = blockIdx.x * 256 + threadIdx.x;
    s[threadIdx.x] = a[i];
    __syncthreads();
    for (int o = 128; o > 0; o >>= 1) {
        if (threadIdx.x < o) s[threadIdx.x] += s[threadIdx.x + o];
        __syncthreads();
    }
    if (threadIdx.x == 0) bs[blockIdx.x] = s[0];
}

__global__ void ks2(int* __restrict__ bs) {   // single block scans NS1 block-sums
    __shared__ int s[256];
    int t = threadIdx.x;
    int v[5];
    int base = t * 5, sum = 0;
#pragma unroll
    for (int k = 0; k < 5; k++) {
        int idx = base + k;
        int x = (idx < NS1) ? bs[idx] : 0;
        v[k] = sum; sum += x;
    }
    s[t] = sum;
    __syncthreads();
    for (int o = 1; o < 256; o <<= 1) {
        int add = (t >= o) ? s[t - o] : 0;
        __syncthreads();
        s[t] += add;
        __syncthreads();
    }
    int excl = (t == 0) ? 0 : s[t - 1];
#pragma unroll
    for (int k = 0; k < 5; k++) {
        int idx = base + k;
        if (idx < NS1) bs[idx] = excl + v[k];
    }
}

__global__ void ks3(int* __restrict__ a, const int* __restrict__ bs) {
    __shared__ int s[256];
    int t = threadIdx.x, i = blockIdx.x * 256 + t;
    int v = a[i];
    s[t] = v;
    __syncthreads();
    for (int o = 1; o < 256; o <<= 1) {
        int add = (t >= o) ? s[t - o] : 0;
        __syncthreads();
        s[t] += add;
        __syncthreads();
    }
    a[i] = s[t] - v + bs[blockIdx.x];
}

// ---------- phase B: scatter records into bucket-grouped buf1 (LDS cursors, no global atomics) ----------
__global__ void __launch_bounds__(256) ksB(const int* __restrict__ ei, const float* __restrict__ ea,
                                           const int* __restrict__ cmat, float4* __restrict__ buf1) {
    __shared__ int base[NBKT];
    for (int i = threadIdx.x; i < NBKT; i += 256) base[i] = cmat[i * NBLKA + blockIdx.x];
    __syncthreads();
    int b0 = blockIdx.x * CHUNK;
    for (int i = threadIdx.x; i < CHUNK; i += 256) {
        int e = b0 + i;
        if (e >= N_EDGES) break;
        int src = ei[e], dst = ei[N_EDGES + e];
        float a0 = ea[(size_t)e * 3 + 0], a1 = ea[(size_t)e * 3 + 1], a2 = ea[(size_t)e * 3 + 2];
        int pos = atomicAdd(&base[dst >> 6], 1);
        buf1[pos] = make_float4(a0, a1, a2, __int_as_float(src | ((dst & 63) << 17)));
    }
}

// ---------- phase C: per-bucket exact CSR (one block per 64-node bucket) ----------
__global__ void __launch_bounds__(256) ksC(const int* __restrict__ cmat, const float4* __restrict__ buf1,
                                           float4* __restrict__ packed, int* __restrict__ offs) {
    __shared__ int cnt[64];
    __shared__ int excl[65];
    int g = blockIdx.x, t = threadIdx.x;
    int bb = cmat[g * NBLKA];
    int be = (g == NBKT - 1) ? N_EDGES : cmat[(g + 1) * NBLKA];
    if (t < 64) cnt[t] = 0;
    __syncthreads();
    for (int j = bb + t; j < be; j += 256) {
        int bits = __float_as_int(buf1[j].w);
        atomicAdd(&cnt[bits >> 17], 1);
    }
    __syncthreads();
    if (t == 0) {
        int a = 0;
        for (int i = 0; i < 64; i++) { excl[i] = a; a += cnt[i]; }
        excl[64] = a;
    }
    __syncthreads();
    if (t < 64) offs[g * 64 + t] = bb + excl[t];
    if (g == NBKT - 1 && t == 0) offs[NPAD] = N_EDGES;
    if (t < 64) cnt[t] = 0;
    __syncthreads();
    for (int j = bb + t; j < be; j += 256) {
        float4 r = buf1[j];
        int bits = __float_as_int(r.w);
        int dl = bits >> 17, src = bits & 0x1FFFF;
        int rank = atomicAdd(&cnt[dl], 1);
        packed[bb + excl[dl] + rank] = make_float4(r.x, r.y, r.z, __int_as_float(src));
    }
}

// ---------- pull aggregation ----------
__global__ void __launch_bounds__(256) k_agg(const float4* __restrict__ packed,
                                             const int* __restrict__ offs,
                                             const float* __restrict__ eW, const float* __restrict__ eb,
                                             const float* __restrict__ h, float* __restrict__ agg) {
    int t = blockIdx.x * 256 + threadIdx.x;
    int n = t >> 3, q = t & 7;
    if (n >= N_NODES) return;
    int c0 = q * 4;
    float w0[4], w1[4], w2[4], bb[4];
#pragma unroll
    for (int i = 0; i < 4; i++) {
        w0[i] = eW[c0 + i];
        w1[i] = eW[32 + c0 + i];
        w2[i] = eW[64 + c0 + i];
        bb[i] = eb[c0 + i];
    }
    int beg = offs[n], end = offs[n + 1];
    float acc[4] = {0.f, 0.f, 0.f, 0.f};
    for (int j = beg; j < end; j++) {
        float4 p = packed[j];
        int src = __float_as_int(p.w);
        float4 hs = *(const float4*)(h + (size_t)src * 32 + c0);
        const float* hp = (const float*)&hs;
#pragma unroll
        for (int i = 0; i < 4; i++) {
            float m = hp[i] + p.x * w0[i] + p.y * w1[i] + p.z * w2[i] + bb[i];
            acc[i] += fmaxf(m, 0.f);
        }
    }
    *(float4*)(agg + (size_t)n * 32 + c0) = make_float4(acc[0], acc[1], acc[2], acc[3]);
}

// ---------- MLP stage 1 ----------
__global__ void __launch_bounds__(256) k_mlp1(const float* __restrict__ h, const float* __restrict__ agg,
                                              const float* __restrict__ W, const float* __restrict__ B,
                                              float* __restrict__ hid) {
    unsigned t = blockIdx.x * 256 + threadIdx.x;
    unsigned n = t / HPAD;
    unsigned j = t - n * HPAD;
    const float4* hp = (const float4*)(h + (size_t)n * 32);
    const float4* ap = (const float4*)(agg + (size_t)n * 32);
    const float4* wp = (const float4*)(W + j * 32);
    float acc0 = 0.f, acc1 = 0.f, acc2 = 0.f, acc3 = 0.f;
#pragma unroll
    for (int q = 0; q < 8; q++) {
        float4 hv = hp[q];
        float4 av = ap[q];
        float4 wv = wp[q];
        acc0 += (hv.x + av.x) * wv.x;
        acc1 += (hv.y + av.y) * wv.y;
        acc2 += (hv.z + av.z) * wv.z;
        acc3 += (hv.w + av.w) * wv.w;
    }
    float v = B[j] + ((acc0 + acc1) + (acc2 + acc3));
    hid[(size_t)n * HPAD + j] = fmaxf(v, 0.f);
}

// ---------- MLP stage 2 ----------
__global__ void __launch_bounds__(256) k_mlp2(const float* __restrict__ hid,
                                              const float* __restrict__ W2T, const float* __restrict__ b2,
                                              float* __restrict__ z) {
    unsigned t = blockIdx.x * 256 + threadIdx.x;
    unsigned n = t >> 5;
    unsigned c = t & 31;
    const float4* hp = (const float4*)(hid + (size_t)n * HPAD);
    const float4* wp = (const float4*)(W2T + c * HPAD);
    float acc0 = 0.f, acc1 = 0.f, acc2 = 0.f, acc3 = 0.f;
#pragma unroll
    for (int q = 0; q < 20; q++) {
        float4 hv = hp[q];
        float4 wv = wp[q];
        acc0 += hv.x * wv.x;
        acc1 += hv.y * wv.y;
        acc2 += hv.z * wv.z;
        acc3 += hv.w * wv.w;
    }
    z[t] = b2[c] + ((acc0 + acc1) + (acc2 + acc3));
}

// ---------- BN stats ----------
__global__ void __launch_bounds__(256) k_stats(const float* __restrict__ z, float* __restrict__ stats) {
    __shared__ float ls[4 * 64];
    int tid = threadIdx.x;
    int c = tid & 31;
    float s = 0.f, s2 = 0.f;
    for (int e = blockIdx.x * 256 + tid; e < N_NODES * 32; e += 256 * 256) {
        float v = z[e];
        s += v; s2 += v * v;
    }
    s += __shfl_down(s, 32, 64);
    s2 += __shfl_down(s2, 32, 64);
    int wave = tid >> 6, lane = tid & 63;
    if (lane < 32) { ls[wave * 64 + c] = s; ls[wave * 64 + 32 + c] = s2; }
    __syncthreads();
    if (tid < 64) {
        float a = ls[tid] + ls[64 + tid] + ls[128 + tid] + ls[192 + tid];
        atomicAdd(&stats[tid], a);
    }
}

// ---------- BN apply + relu ----------
__global__ void k_bn(const float* __restrict__ z, float* __restrict__ h,
                     const float* __restrict__ stats, const float* __restrict__ g,
                     const float* __restrict__ b) {
    int t = blockIdx.x * 256 + threadIdx.x;
    if (t >= N_NODES * 8) return;
    int q = t & 7;
    float4 zv = ((const float4*)z)[t];
    float* zp = (float*)&zv;
    float4 ov;
    float* op = (float*)&ov;
    const float invN = 1.0f / (float)N_NODES;
#pragma unroll
    for (int i = 0; i < 4; i++) {
        int c = q * 4 + i;
        float mu = stats[c] * invN;
        float var = stats[32 + c] * invN - mu * mu;
        float sc = g[c] / sqrtf(var + BN_EPS);
        op[i] = fmaxf((zp[i] - mu) * sc + b[c], 0.f);
    }
    ((float4*)h)[t] = ov;
}

// ---------- graph offsets via binary search (batch is sorted) ----------
__global__ void k_goff(const int* __restrict__ batch, int* __restrict__ goff) {
    int g = blockIdx.x * 256 + threadIdx.x;
    if (g > N_GRAPHS) return;
    int lo = 0, hi = N_NODES;
    while (lo < hi) {
        int mid = (lo + hi) >> 1;
        if (batch[mid] < g) lo = mid + 1; else hi = mid;
    }
    goff[g] = lo;
}

// ---------- mean-pool: one wave per graph, segmented sum, no atomics ----------
__global__ void __launch_bounds__(256) k_pool2(const float* __restrict__ h, const int* __restrict__ goff,
                                               float* __restrict__ gsum) {
    int wid = threadIdx.x >> 6, lane = threadIdx.x & 63;
    int g = blockIdx.x * 4 + wid;
    if (g >= N_GRAPHS) return;
    int s = goff[g], e = goff[g + 1];
    int c = lane & 31, half = lane >> 5;
    float acc = 0.f;
    for (int n = s + half; n < e; n += 2) acc += h[(size_t)n * 32 + c];
    acc += __shfl_down(acc, 32, 64);
    if (lane < 32) gsum[(size_t)g * 32 + c] = acc;
}

__global__ void k_head(const float* __restrict__ gsum, const int* __restrict__ goff,
                       const float* __restrict__ W1, const float* __restrict__ b1,
                       const float* __restrict__ W2, const float* __restrict__ b2,
                       float* __restrict__ out) {
    __shared__ float sW1[512], sb1[16], sW2[32], sb2[2];
    for (int i = threadIdx.x; i < 512; i += 256) sW1[i] = W1[i];
    if (threadIdx.x < 16) sb1[threadIdx.x] = b1[threadIdx.x];
    if (threadIdx.x < 32) sW2[threadIdx.x] = W2[threadIdx.x];
    if (threadIdx.x < 2) sb2[threadIdx.x] = b2[threadIdx.x];
    __syncthreads();
    int gI = blockIdx.x * 256 + threadIdx.x;
    if (gI >= N_GRAPHS) return;
    float cnt = (float)(goff[gI + 1] - goff[gI]);
    float inv = 1.0f / fmaxf(cnt, 1.0f);
    float gx[32];
#pragma unroll
    for (int c = 0; c < 32; c++) gx[c] = gsum[(size_t)gI * 32 + c] * inv;
    float hid[16];
#pragma unroll
    for (int j = 0; j < 16; j++) {
        float a = sb1[j];
#pragma unroll
        for (int c = 0; c < 32; c++) a += gx[c] * sW1[c * 16 + j];
        hid[j] = fmaxf(a, 0.f);
    }
#pragma unroll
    for (int o = 0; o < 2; o++) {
        float a = sb2[o];
#pragma unroll
        for (int j = 0; j < 16; j++) a += hid[j] * sW2[j * 2 + o];
        out[(size_t)gI * 2 + o] = a;
    }
}

extern "C" void kernel_launch(void* const* d_in, const int* in_sizes, int n_in,
                              void* d_out, int out_size, void* d_ws, size_t ws_size,
                              hipStream_t stream) {
    const float* x       = (const float*)d_in[0];
    const int*   ei      = (const int*)d_in[1];
    const float* eattr   = (const float*)d_in[2];
    const int*   batch   = (const int*)d_in[3];
    const float* node_w  = (const float*)d_in[4];
    const float* node_b  = (const float*)d_in[5];
    const float* edge_w  = (const float*)d_in[6];
    const float* edge_b  = (const float*)d_in[7];
    const float* conv_w1 = (const float*)d_in[8];
    const float* conv_b1 = (const float*)d_in[9];
    const float* conv_w2 = (const float*)d_in[10];
    const float* conv_b2 = (const float*)d_in[11];
    const float* bn_g    = (const float*)d_in[12];
    const float* bn_b    = (const float*)d_in[13];
    const float* lin1_w  = (const float*)d_in[14];
    const float* lin1_b  = (const float*)d_in[15];
    const float* lin2_w  = (const float*)d_in[16];
    const float* lin2_b  = (const float*)d_in[17];
    float* out = (float*)d_out;

    // workspace layout; buf1 (CSR build) and hid (layer loop) alias the same region
    float4* packed = (float4*)d_ws;                        // 51.2 MB
    float4* buf1   = packed + N_EDGES;                     // 51.2 MB
    float*  hid    = (float*)buf1;                         // alias (32 MB, disjoint lifetime)
    float*  h      = (float*)(buf1 + N_EDGES);             // 12.8 MB
    float*  agg    = h + (size_t)N_NODES * 32;             // 12.8 MB
    int*    cmat   = (int*)(agg + (size_t)N_NODES * 32);   // LALLOC ints
    int*    t1     = cmat + LALLOC;                        // 1280
    int*    offs   = t1 + 1280;                            // NPAD+1
    int*    goff   = offs + NPAD + 1;                      // N_GRAPHS+1
    float*  stats  = (float*)(goff + N_GRAPHS + 1);        // 64
    float*  gsum   = stats + 64;                           // G*32
    float*  w1tp   = gsum + (size_t)N_GRAPHS * 32;         // 2*80*32
    float*  b1p    = w1tp + 2 * HPAD * 32;                 // 2*80
    float*  w2tp   = b1p + 2 * HPAD;                       // 2*32*80

    int nb_nodes = (N_NODES + 255) / 256;
    int nb_vec   = (N_NODES * 8 + 255) / 256;

    hipMemsetAsync(cmat, 0, LALLOC * sizeof(int), stream);
    k_encode<<<nb_nodes, 256, 0, stream>>>(x, node_w, node_b, h);
    k_prep<<<(2 * HPAD * 32 + 2 * HPAD + 2 * 32 * HPAD + 255) / 256, 256, 0, stream>>>(
        conv_w1, conv_b1, conv_w2, w1tp, b1p, w2tp);
    k_goff<<<(N_GRAPHS + 1 + 255) / 256, 256, 0, stream>>>(batch, goff);

    // atomic-free CSR build
    ksA<<<NBLKA, 256, 0, stream>>>(ei, cmat);
    ks1<<<NS1, 256, 0, stream>>>(cmat, t1);
    ks2<<<1, 256, 0, stream>>>(t1);
    ks3<<<NS1, 256, 0, stream>>>(cmat, t1);
    ksB<<<NBLKA, 256, 0, stream>>>(ei, eattr, cmat, buf1);
    ksC<<<NBKT, 256, 0, stream>>>(cmat, buf1, packed, offs);

    for (int l = 0; l < 2; l++) {
        hipMemsetAsync(stats, 0, 64 * sizeof(float), stream);
        k_agg<<<NPAD * 8 / 256, 256, 0, stream>>>(packed, offs, edge_w, edge_b, h, agg);
        k_mlp1<<<N_NODES * HPAD / 256, 256, 0, stream>>>(h, agg, w1tp + l * HPAD * 32,
                                                         b1p + l * HPAD, hid);
        k_mlp2<<<N_NODES * 32 / 256, 256, 0, stream>>>(hid, w2tp + l * 32 * HPAD,
                                                       conv_b2 + l * 32, agg);
        k_stats<<<256, 256, 0, stream>>>(agg, stats);
        k_bn<<<nb_vec, 256, 0, stream>>>(agg, h, stats, bn_g + l * 32, bn_b + l * 32);
    }
    k_pool2<<<(N_GRAPHS + 3) / 4, 256, 0, stream>>>(h, goff, gsum);
    k_head<<<(N_GRAPHS + 255) / 256, 256, 0, stream>>>(gsum, goff, lin1_w, lin1_b, lin2_w, lin2_b, out);
}

// Round 7
// 850.949 us; speedup vs baseline: 2.2026x; 1.2146x over previous
//
#include <hip/hip_runtime.h>

#define N_NODES 100000
#define N_EDGES 3200000
#define N_GRAPHS 5000
#define BN_EPS 1e-5f
#define NPAD 100096    // 1564 * 64
#define HPAD 80        // hidden 75 padded to 80
#define CHUNK 16384    // edges per bucket-sort block
#define NBLKA 196      // ceil(N_EDGES / CHUNK)
#define NBKT 1564      // buckets of 64 nodes (dst >> 6)
#define LCM (NBKT * NBLKA)
#define LALLOC 306688  // LCM padded to 1198*256
#define NS1 1198       // LALLOC / 256

// ---------- node encoder: h = x @ node_w + node_b ----------
__global__ void k_encode(const float* __restrict__ x, const float* __restrict__ W,
                         const float* __restrict__ b, float* __restrict__ h) {
    __shared__ float sW[448];
    __shared__ float sb[32];
    for (int i = threadIdx.x; i < 448; i += 256) sW[i] = W[i];
    if (threadIdx.x < 32) sb[threadIdx.x] = b[threadIdx.x];
    __syncthreads();
    int n = blockIdx.x * 256 + threadIdx.x;
    if (n >= N_NODES) return;
    float xi[14];
#pragma unroll
    for (int k = 0; k < 14; k++) xi[k] = x[n * 14 + k];
    float4* hp = (float4*)(h + (size_t)n * 32);
#pragma unroll
    for (int q = 0; q < 8; q++) {
        float4 acc;
        float* ap = (float*)&acc;
#pragma unroll
        for (int i = 0; i < 4; i++) {
            int c = q * 4 + i;
            float a = sb[c];
#pragma unroll
            for (int k = 0; k < 14; k++) a += xi[k] * sW[k * 32 + c];
            ap[i] = a;
        }
        hp[q] = acc;
    }
}

// ---------- weight prep ----------
// w1tp[l][j(80)][c(32)] transposed, rows j>=75 zero; b1p[l][j(80)] zero-padded;
// w2p [l][j(80)][c(32)] zero-padded copy (no transpose)
__global__ void k_prep(const float* __restrict__ W1, const float* __restrict__ b1,
                       const float* __restrict__ W2,
                       float* __restrict__ w1tp, float* __restrict__ b1p,
                       float* __restrict__ w2p) {
    int i = blockIdx.x * 256 + threadIdx.x;
    if (i < 2 * HPAD * 32) {
        int l = i / (HPAD * 32), r = i % (HPAD * 32);
        int j = r / 32, c = r % 32;
        w1tp[i] = (j < 75) ? W1[l * 2400 + c * 75 + j] : 0.f;
        w2p[i]  = (j < 75) ? W2[l * 2400 + j * 32 + c] : 0.f;
    } else if (i < 2 * HPAD * 32 + 2 * HPAD) {
        int k = i - 2 * HPAD * 32;
        int l = k / HPAD, j = k % HPAD;
        b1p[k] = (j < 75) ? b1[l * 75 + j] : 0.f;
    }
}

// ---------- bucket sort phase A ----------
__global__ void __launch_bounds__(256) ksA(const int* __restrict__ ei, int* __restrict__ cmat) {
    __shared__ int lh[NBKT];
    for (int i = threadIdx.x; i < NBKT; i += 256) lh[i] = 0;
    __syncthreads();
    int b0 = blockIdx.x * CHUNK;
    for (int i = threadIdx.x; i < CHUNK; i += 256) {
        int e = b0 + i;
        if (e < N_EDGES) atomicAdd(&lh[ei[N_EDGES + e] >> 6], 1);
    }
    __syncthreads();
    for (int b = threadIdx.x; b < NBKT; b += 256) cmat[b * NBLKA + blockIdx.x] = lh[b];
}

// ---------- parallel exclusive scan of cmat ----------
__global__ void ks1(const int* __restrict__ a, int* __restrict__ bs) {
    __shared__ int s[256];
    int i = blockIdx.x * 256 + threadIdx.x;
    s[threadIdx.x] = a[i];
    __syncthreads();
    for (int o = 128; o > 0; o >>= 1) {
        if (threadIdx.x < o) s[threadIdx.x] += s[threadIdx.x + o];
        __syncthreads();
    }
    if (threadIdx.x == 0) bs[blockIdx.x] = s[0];
}

__global__ void ks2(int* __restrict__ bs) {
    __shared__ int s[256];
    int t = threadIdx.x;
    int v[5];
    int base = t * 5, sum = 0;
#pragma unroll
    for (int k = 0; k < 5; k++) {
        int idx = base + k;
        int x = (idx < NS1) ? bs[idx] : 0;
        v[k] = sum; sum += x;
    }
    s[t] = sum;
    __syncthreads();
    for (int o = 1; o < 256; o <<= 1) {
        int add = (t >= o) ? s[t - o] : 0;
        __syncthreads();
        s[t] += add;
        __syncthreads();
    }
    int excl = (t == 0) ? 0 : s[t - 1];
#pragma unroll
    for (int k = 0; k < 5; k++) {
        int idx = base + k;
        if (idx < NS1) bs[idx] = excl + v[k];
    }
}

__global__ void ks3(int* __restrict__ a, const int* __restrict__ bs) {
    __shared__ int s[256];
    int t = threadIdx.x, i = blockIdx.x * 256 + t;
    int v = a[i];
    s[t] = v;
    __syncthreads();
    for (int o = 1; o < 256; o <<= 1) {
        int add = (t >= o) ? s[t - o] : 0;
        __syncthreads();
        s[t] += add;
        __syncthreads();
    }
    a[i] = s[t] - v + bs[blockIdx.x];
}

// ---------- phase B: scatter to bucket-grouped buf1 ----------
__global__ void __launch_bounds__(256) ksB(const int* __restrict__ ei, const float* __restrict__ ea,
                                           const int* __restrict__ cmat, float4* __restrict__ buf1) {
    __shared__ int base[NBKT];
    for (int i = threadIdx.x; i < NBKT; i += 256) base[i] = cmat[i * NBLKA + blockIdx.x];
    __syncthreads();
    int b0 = blockIdx.x * CHUNK;
    for (int i = threadIdx.x; i < CHUNK; i += 256) {
        int e = b0 + i;
        if (e >= N_EDGES) break;
        int src = ei[e], dst = ei[N_EDGES + e];
        float a0 = ea[(size_t)e * 3 + 0], a1 = ea[(size_t)e * 3 + 1], a2 = ea[(size_t)e * 3 + 2];
        int pos = atomicAdd(&base[dst >> 6], 1);
        buf1[pos] = make_float4(a0, a1, a2, __int_as_float(src | ((dst & 63) << 17)));
    }
}

// ---------- phase C: per-bucket exact CSR ----------
__global__ void __launch_bounds__(256) ksC(const int* __restrict__ cmat, const float4* __restrict__ buf1,
                                           float4* __restrict__ packed, int* __restrict__ offs) {
    __shared__ int cnt[64];
    __shared__ int excl[65];
    int g = blockIdx.x, t = threadIdx.x;
    int bb = cmat[g * NBLKA];
    int be = (g == NBKT - 1) ? N_EDGES : cmat[(g + 1) * NBLKA];
    if (t < 64) cnt[t] = 0;
    __syncthreads();
    for (int j = bb + t; j < be; j += 256) {
        int bits = __float_as_int(buf1[j].w);
        atomicAdd(&cnt[bits >> 17], 1);
    }
    __syncthreads();
    if (t == 0) {
        int a = 0;
        for (int i = 0; i < 64; i++) { excl[i] = a; a += cnt[i]; }
        excl[64] = a;
    }
    __syncthreads();
    if (t < 64) offs[g * 64 + t] = bb + excl[t];
    if (g == NBKT - 1 && t == 0) offs[NPAD] = N_EDGES;
    if (t < 64) cnt[t] = 0;
    __syncthreads();
    for (int j = bb + t; j < be; j += 256) {
        float4 r = buf1[j];
        int bits = __float_as_int(r.w);
        int dl = bits >> 17, src = bits & 0x1FFFF;
        int rank = atomicAdd(&cnt[dl], 1);
        packed[bb + excl[dl] + rank] = make_float4(r.x, r.y, r.z, __int_as_float(src));
    }
}

// ---------- pull aggregation: 16 threads/node (2-way edge split, shfl combine) ----------
__global__ void __launch_bounds__(256) k_agg(const float4* __restrict__ packed,
                                             const int* __restrict__ offs,
                                             const float* __restrict__ eW, const float* __restrict__ eb,
                                             const float* __restrict__ h, float* __restrict__ agg) {
    int t = blockIdx.x * 256 + threadIdx.x;   // N_NODES*16 exact
    int n = t >> 4, s = t & 15;
    int q = s & 7, half = s >> 3;
    int c0 = q * 4;
    float w0[4], w1[4], w2[4], bb[4];
#pragma unroll
    for (int i = 0; i < 4; i++) {
        w0[i] = eW[c0 + i];
        w1[i] = eW[32 + c0 + i];
        w2[i] = eW[64 + c0 + i];
        bb[i] = eb[c0 + i];
    }
    int beg = offs[n], end = offs[n + 1];
    float acc[4] = {0.f, 0.f, 0.f, 0.f};
    for (int j = beg + half; j < end; j += 2) {
        float4 p = packed[j];
        int src = __float_as_int(p.w);
        float4 hs = *(const float4*)(h + (size_t)src * 32 + c0);
        const float* hp = (const float*)&hs;
#pragma unroll
        for (int i = 0; i < 4; i++) {
            float m = hp[i] + p.x * w0[i] + p.y * w1[i] + p.z * w2[i] + bb[i];
            acc[i] += fmaxf(m, 0.f);
        }
    }
#pragma unroll
    for (int i = 0; i < 4; i++) acc[i] += __shfl_xor(acc[i], 8, 64);
    if (half == 0)
        *(float4*)(agg + (size_t)n * 32 + c0) = make_float4(acc[0], acc[1], acc[2], acc[3]);
}

// ---------- fused MLP: z = relu((h+agg)@W1+b1)@W2+b2, written over agg ----------
// 8 lanes per node; lane oct computes hidden units j=oct*10..+10 and lane-relative
// output partials pzo[r] for channel-quad (oct+r)&7; 7-step shfl rotation delivers
// each lane its own quad. No hid materialization, no dynamic register indexing.
__global__ void __launch_bounds__(256) k_mlp(const float* __restrict__ h, float* __restrict__ agg,
                                             const float* __restrict__ W1, const float* __restrict__ B1,
                                             const float* __restrict__ W2, const float* __restrict__ b2) {
    unsigned t = blockIdx.x * 256 + threadIdx.x;   // N_NODES*8 exact
    unsigned n = t >> 3, oct = t & 7;
    const float4* hp = (const float4*)(h + (size_t)n * 32);
    const float4* ap = (const float4*)(agg + (size_t)n * 32);
    float zc[32];
#pragma unroll
    for (int q = 0; q < 8; q++) {
        float4 hv = hp[q], av = ap[q];
        zc[q * 4 + 0] = hv.x + av.x;
        zc[q * 4 + 1] = hv.y + av.y;
        zc[q * 4 + 2] = hv.z + av.z;
        zc[q * 4 + 3] = hv.w + av.w;
    }
    // stage 1: 10 hidden units per lane
    float hid[10];
#pragma unroll
    for (int i = 0; i < 10; i++) {
        int j = oct * 10 + i;
        const float4* wp = (const float4*)(W1 + j * 32);
        float a0 = 0.f, a1 = 0.f, a2 = 0.f, a3 = 0.f;
#pragma unroll
        for (int q = 0; q < 8; q++) {
            float4 wv = wp[q];
            a0 += zc[q * 4 + 0] * wv.x;
            a1 += zc[q * 4 + 1] * wv.y;
            a2 += zc[q * 4 + 2] * wv.z;
            a3 += zc[q * 4 + 3] * wv.w;
        }
        hid[i] = fmaxf(B1[j] + ((a0 + a1) + (a2 + a3)), 0.f);
    }
    // stage 2: lane-relative output partials
    float pzo[8][4];
#pragma unroll
    for (int r = 0; r < 8; r++) {
        pzo[r][0] = 0.f; pzo[r][1] = 0.f; pzo[r][2] = 0.f; pzo[r][3] = 0.f;
    }
#pragma unroll
    for (int i = 0; i < 10; i++) {
        int j = oct * 10 + i;
        const float* w2row = W2 + j * 32;
        float hj = hid[i];
#pragma unroll
        for (int r = 0; r < 8; r++) {
            int q = (oct + r) & 7;
            float4 wv = *(const float4*)(w2row + q * 4);
            pzo[r][0] += hj * wv.x;
            pzo[r][1] += hj * wv.y;
            pzo[r][2] += hj * wv.z;
            pzo[r][3] += hj * wv.w;
        }
    }
    // rotation reduce: lane with oct Q sums, over r, pzo[r] from lane oct=(Q-r)&7
    int lane = threadIdx.x & 63;
    int gbase = lane & 0x38;
    float zo0 = pzo[0][0], zo1 = pzo[0][1], zo2 = pzo[0][2], zo3 = pzo[0][3];
#pragma unroll
    for (int r = 1; r < 8; r++) {
        int srcl = gbase | ((int)(oct + 8 - r) & 7);
        zo0 += __shfl(pzo[r][0], srcl, 64);
        zo1 += __shfl(pzo[r][1], srcl, 64);
        zo2 += __shfl(pzo[r][2], srcl, 64);
        zo3 += __shfl(pzo[r][3], srcl, 64);
    }
    float4 bv = *(const float4*)(b2 + oct * 4);
    *(float4*)(agg + (size_t)n * 32 + oct * 4) =
        make_float4(zo0 + bv.x, zo1 + bv.y, zo2 + bv.z, zo3 + bv.w);
}

// ---------- BN stats ----------
__global__ void __launch_bounds__(256) k_stats(const float* __restrict__ z, float* __restrict__ stats) {
    __shared__ float ls[4 * 64];
    int tid = threadIdx.x;
    int c = tid & 31;
    float s = 0.f, s2 = 0.f;
    for (int e = blockIdx.x * 256 + tid; e < N_NODES * 32; e += 256 * 256) {
        float v = z[e];
        s += v; s2 += v * v;
    }
    s += __shfl_down(s, 32, 64);
    s2 += __shfl_down(s2, 32, 64);
    int wave = tid >> 6, lane = tid & 63;
    if (lane < 32) { ls[wave * 64 + c] = s; ls[wave * 64 + 32 + c] = s2; }
    __syncthreads();
    if (tid < 64) {
        float a = ls[tid] + ls[64 + tid] + ls[128 + tid] + ls[192 + tid];
        atomicAdd(&stats[tid], a);
    }
}

// ---------- BN apply + relu ----------
__global__ void k_bn(const float* __restrict__ z, float* __restrict__ h,
                     const float* __restrict__ stats, const float* __restrict__ g,
                     const float* __restrict__ b) {
    int t = blockIdx.x * 256 + threadIdx.x;
    if (t >= N_NODES * 8) return;
    int q = t & 7;
    float4 zv = ((const float4*)z)[t];
    float* zp = (float*)&zv;
    float4 ov;
    float* op = (float*)&ov;
    const float invN = 1.0f / (float)N_NODES;
#pragma unroll
    for (int i = 0; i < 4; i++) {
        int c = q * 4 + i;
        float mu = stats[c] * invN;
        float var = stats[32 + c] * invN - mu * mu;
        float sc = g[c] / sqrtf(var + BN_EPS);
        op[i] = fmaxf((zp[i] - mu) * sc + b[c], 0.f);
    }
    ((float4*)h)[t] = ov;
}

// ---------- graph offsets (batch is sorted) ----------
__global__ void k_goff(const int* __restrict__ batch, int* __restrict__ goff) {
    int g = blockIdx.x * 256 + threadIdx.x;
    if (g > N_GRAPHS) return;
    int lo = 0, hi = N_NODES;
    while (lo < hi) {
        int mid = (lo + hi) >> 1;
        if (batch[mid] < g) lo = mid + 1; else hi = mid;
    }
    goff[g] = lo;
}

// ---------- mean-pool: one wave per graph ----------
__global__ void __launch_bounds__(256) k_pool2(const float* __restrict__ h, const int* __restrict__ goff,
                                               float* __restrict__ gsum) {
    int wid = threadIdx.x >> 6, lane = threadIdx.x & 63;
    int g = blockIdx.x * 4 + wid;
    if (g >= N_GRAPHS) return;
    int s = goff[g], e = goff[g + 1];
    int c = lane & 31, half = lane >> 5;
    float acc = 0.f;
    for (int n = s + half; n < e; n += 2) acc += h[(size_t)n * 32 + c];
    acc += __shfl_down(acc, 32, 64);
    if (lane < 32) gsum[(size_t)g * 32 + c] = acc;
}

__global__ void k_head(const float* __restrict__ gsum, const int* __restrict__ goff,
                       const float* __restrict__ W1, const float* __restrict__ b1,
                       const float* __restrict__ W2, const float* __restrict__ b2,
                       float* __restrict__ out) {
    __shared__ float sW1[512], sb1[16], sW2[32], sb2[2];
    for (int i = threadIdx.x; i < 512; i += 256) sW1[i] = W1[i];
    if (threadIdx.x < 16) sb1[threadIdx.x] = b1[threadIdx.x];
    if (threadIdx.x < 32) sW2[threadIdx.x] = W2[threadIdx.x];
    if (threadIdx.x < 2) sb2[threadIdx.x] = b2[threadIdx.x];
    __syncthreads();
    int gI = blockIdx.x * 256 + threadIdx.x;
    if (gI >= N_GRAPHS) return;
    float cnt = (float)(goff[gI + 1] - goff[gI]);
    float inv = 1.0f / fmaxf(cnt, 1.0f);
    float gx[32];
#pragma unroll
    for (int c = 0; c < 32; c++) gx[c] = gsum[(size_t)gI * 32 + c] * inv;
    float hid[16];
#pragma unroll
    for (int j = 0; j < 16; j++) {
        float a = sb1[j];
#pragma unroll
        for (int c = 0; c < 32; c++) a += gx[c] * sW1[c * 16 + j];
        hid[j] = fmaxf(a, 0.f);
    }
#pragma unroll
    for (int o = 0; o < 2; o++) {
        float a = sb2[o];
#pragma unroll
        for (int j = 0; j < 16; j++) a += hid[j] * sW2[j * 2 + o];
        out[(size_t)gI * 2 + o] = a;
    }
}

extern "C" void kernel_launch(void* const* d_in, const int* in_sizes, int n_in,
                              void* d_out, int out_size, void* d_ws, size_t ws_size,
                              hipStream_t stream) {
    const float* x       = (const float*)d_in[0];
    const int*   ei      = (const int*)d_in[1];
    const float* eattr   = (const float*)d_in[2];
    const int*   batch   = (const int*)d_in[3];
    const float* node_w  = (const float*)d_in[4];
    const float* node_b  = (const float*)d_in[5];
    const float* edge_w  = (const float*)d_in[6];
    const float* edge_b  = (const float*)d_in[7];
    const float* conv_w1 = (const float*)d_in[8];
    const float* conv_b1 = (const float*)d_in[9];
    const float* conv_w2 = (const float*)d_in[10];
    const float* conv_b2 = (const float*)d_in[11];
    const float* bn_g    = (const float*)d_in[12];
    const float* bn_b    = (const float*)d_in[13];
    const float* lin1_w  = (const float*)d_in[14];
    const float* lin1_b  = (const float*)d_in[15];
    const float* lin2_w  = (const float*)d_in[16];
    const float* lin2_b  = (const float*)d_in[17];
    float* out = (float*)d_out;

    float4* packed = (float4*)d_ws;                        // 51.2 MB
    float4* buf1   = packed + N_EDGES;                     // 51.2 MB (CSR build only)
    float*  h      = (float*)(buf1 + N_EDGES);             // 12.8 MB
    float*  agg    = h + (size_t)N_NODES * 32;             // 12.8 MB (z in-place)
    int*    cmat   = (int*)(agg + (size_t)N_NODES * 32);   // LALLOC ints
    int*    t1     = cmat + LALLOC;                        // 1280
    int*    offs   = t1 + 1280;                            // NPAD+1
    int*    goff   = offs + NPAD + 1;                      // N_GRAPHS+1
    float*  stats  = (float*)(goff + N_GRAPHS + 1);        // 64
    float*  gsum   = stats + 64;                           // G*32
    float*  w1tp   = gsum + (size_t)N_GRAPHS * 32;         // 2*80*32
    float*  b1p    = w1tp + 2 * HPAD * 32;                 // 2*80
    float*  w2p    = b1p + 2 * HPAD;                       // 2*80*32

    int nb_nodes = (N_NODES + 255) / 256;
    int nb_vec   = (N_NODES * 8 + 255) / 256;

    hipMemsetAsync(cmat, 0, LALLOC * sizeof(int), stream);
    k_encode<<<nb_nodes, 256, 0, stream>>>(x, node_w, node_b, h);
    k_prep<<<(2 * HPAD * 32 + 2 * HPAD + 255) / 256, 256, 0, stream>>>(
        conv_w1, conv_b1, conv_w2, w1tp, b1p, w2p);
    k_goff<<<(N_GRAPHS + 1 + 255) / 256, 256, 0, stream>>>(batch, goff);

    ksA<<<NBLKA, 256, 0, stream>>>(ei, cmat);
    ks1<<<NS1, 256, 0, stream>>>(cmat, t1);
    ks2<<<1, 256, 0, stream>>>(t1);
    ks3<<<NS1, 256, 0, stream>>>(cmat, t1);
    ksB<<<NBLKA, 256, 0, stream>>>(ei, eattr, cmat, buf1);
    ksC<<<NBKT, 256, 0, stream>>>(cmat, buf1, packed, offs);

    for (int l = 0; l < 2; l++) {
        hipMemsetAsync(stats, 0, 64 * sizeof(float), stream);
        k_agg<<<N_NODES * 16 / 256, 256, 0, stream>>>(packed, offs, edge_w, edge_b, h, agg);
        k_mlp<<<N_NODES * 8 / 256, 256, 0, stream>>>(h, agg, w1tp + l * HPAD * 32,
                                                     b1p + l * HPAD, w2p + l * HPAD * 32,
                                                     conv_b2 + l * 32);
        k_stats<<<256, 256, 0, stream>>>(agg, stats);
        k_bn<<<nb_vec, 256, 0, stream>>>(agg, h, stats, bn_g + l * 32, bn_b + l * 32);
    }
    k_pool2<<<(N_GRAPHS + 3) / 4, 256, 0, stream>>>(h, goff, gsum);
    k_head<<<(N_GRAPHS + 255) / 256, 256, 0, stream>>>(gsum, goff, lin1_w, lin1_b, lin2_w, lin2_b, out);
}